// Round 3
// baseline (432.700 us; speedup 1.0000x reference)
//
#include <hip/hip_runtime.h>
#include <math.h>

typedef float f32x4 __attribute__((ext_vector_type(4)));
typedef __bf16 bf16x8 __attribute__((ext_vector_type(8)));

// ---------------------------------------------------------------------------
// CSR row offsets from sorted self_fea_idx. row_start[N] = M.
// ---------------------------------------------------------------------------
__global__ void build_row_start(const int* __restrict__ self_idx,
                                int* __restrict__ row_start, int M, int N) {
  int i = blockIdx.x * blockDim.x + threadIdx.x;
  if (i >= M) return;
  int cur = self_idx[i];
  int prev = (i == 0) ? -1 : self_idx[i - 1];
  for (int j = prev + 1; j <= cur; ++j) row_start[j] = i;
  if (i == M - 1) {
    for (int j = cur + 1; j <= N; ++j) row_start[j] = M;
  }
}

// ---------------------------------------------------------------------------
// Phase A: per-atom precompute of layer-1 halves.
//   U'[a][d] = sum_k X[a][k]*W1[k][d] + b1[d]   (k = 0..63, "self" half)
//   Y [a][d] = sum_k X[a][k]*W1[64+k][d]        ("nbr" half)
// Stored bf16. One wave per 16-atom tile, MFMA 16x16x32.
// A-frag: lane holds A[row=lane&15][k=(lane>>4)*8 + j], j=0..7.
// B-frag: lane holds B[k=(lane>>4)*8 + j][col=lane&15].
// C     : lane holds C[row=(lane>>4)*4 + reg][col=lane&15].
// 256-thread blocks = 4 independent waves (wave-stride over tiles).
// ---------------------------------------------------------------------------
__global__ __launch_bounds__(256, 2)
void precompute_uy(const float* __restrict__ atom_fea,
                   const float* __restrict__ W1,
                   const float* __restrict__ b1,
                   __bf16* __restrict__ Ub, __bf16* __restrict__ Yb, int N) {
  const int lane = threadIdx.x & 63;
  const int r16 = lane & 15, g = lane >> 4;
  const int wid = (blockIdx.x * blockDim.x + threadIdx.x) >> 6;
  const int nw = (gridDim.x * blockDim.x) >> 6;

  bf16x8 wt[2][4], wb[2][4];
#pragma unroll
  for (int ks = 0; ks < 2; ++ks)
#pragma unroll
    for (int c = 0; c < 4; ++c) {
      bf16x8 t, b;
#pragma unroll
      for (int jj = 0; jj < 8; ++jj) {
        int k = 32 * ks + 8 * g + jj;
        t[jj] = (__bf16)W1[(size_t)k * 64 + 16 * c + r16];
        b[jj] = (__bf16)W1[(size_t)(64 + k) * 64 + 16 * c + r16];
      }
      wt[ks][c] = t; wb[ks][c] = b;
    }
  float b1c[4];
#pragma unroll
  for (int c = 0; c < 4; ++c) b1c[c] = b1[16 * c + r16];

  const int nTiles = (N + 15) >> 4;
  for (int tile = wid; tile < nTiles; tile += nw) {
    const int a0 = tile * 16;
    int arow = a0 + r16; if (arow >= N) arow = N - 1;

    bf16x8 af[2];
#pragma unroll
    for (int ks = 0; ks < 2; ++ks) {
      const float* p = atom_fea + (size_t)arow * 64 + 32 * ks + 8 * g;
      f32x4 x0 = *(const f32x4*)p;
      f32x4 x1 = *(const f32x4*)(p + 4);
      bf16x8 a;
#pragma unroll
      for (int jj = 0; jj < 4; ++jj) { a[jj] = (__bf16)x0[jj]; a[4 + jj] = (__bf16)x1[jj]; }
      af[ks] = a;
    }

    f32x4 uacc[4], yacc[4];
#pragma unroll
    for (int c = 0; c < 4; ++c) { uacc[c] = (f32x4)0.0f; yacc[c] = (f32x4)0.0f; }
#pragma unroll
    for (int ks = 0; ks < 2; ++ks)
#pragma unroll
      for (int c = 0; c < 4; ++c) {
        uacc[c] = __builtin_amdgcn_mfma_f32_16x16x32_bf16(af[ks], wt[ks][c], uacc[c], 0, 0, 0);
        yacc[c] = __builtin_amdgcn_mfma_f32_16x16x32_bf16(af[ks], wb[ks][c], yacc[c], 0, 0, 0);
      }

#pragma unroll
    for (int c = 0; c < 4; ++c)
#pragma unroll
      for (int j = 0; j < 4; ++j) {
        int row = a0 + 4 * g + j;
        if (row < N) {
          Ub[(size_t)row * 64 + 16 * c + r16] = (__bf16)(uacc[c][j] + b1c[c]);
          Yb[(size_t)row * 64 + 16 * c + r16] = (__bf16)yacc[c][j];
        }
      }
  }
}

// ---------------------------------------------------------------------------
// Main fused kernel: one wave per segment, 16-edge MFMA tiles, online softmax.
// No LDS, no barriers. 256-thread blocks = 4 independent waves so the
// workgroup-per-CU cap doesn't bind (8 blocks x 4 waves = 32 waves/CU).
// ---------------------------------------------------------------------------
__global__ __launch_bounds__(256, 8)
void fused_pool(const float* __restrict__ atom_w,
                const float* __restrict__ atom_fea,
                const int* __restrict__ nbr_idx,
                const float* __restrict__ W2,
                const float* __restrict__ b2,
                const float* __restrict__ Wg,
                const float* __restrict__ bg,
                const int* __restrict__ row_start,
                const __bf16* __restrict__ Ub,
                const __bf16* __restrict__ Yb,
                float* __restrict__ out, int N) {
  const int lane = threadIdx.x & 63;
  const int r16 = lane & 15, g = lane >> 4;
  const int wid = (blockIdx.x * blockDim.x + threadIdx.x) >> 6;
  const int nw = (gridDim.x * blockDim.x) >> 6;

  // W2 B-frags
  bf16x8 w2f[2][4];
#pragma unroll
  for (int ks = 0; ks < 2; ++ks)
#pragma unroll
    for (int c = 0; c < 4; ++c) {
      bf16x8 t;
#pragma unroll
      for (int jj = 0; jj < 8; ++jj) {
        int k = 32 * ks + 8 * g + jj;
        t[jj] = (__bf16)W2[(size_t)k * 64 + 16 * c + r16];
      }
      w2f[ks][c] = t;
    }
  float b2c[4];
#pragma unroll
  for (int c = 0; c < 4; ++c) b2c[c] = b2[16 * c + r16];

  // wg2[k] = sum_d W2[k][d]*Wg[d]  (lane holds k = lane)
  float wgl = 0.f;
  {
    const float* w2row = W2 + (size_t)lane * 64;
#pragma unroll
    for (int d = 0; d < 64; ++d) wgl = fmaf(w2row[d], Wg[d], wgl);
  }
  // bgp = bg + sum_d b2[d]*Wg[d]
  float tb = b2[lane] * Wg[lane];
#pragma unroll
  for (int off = 1; off < 64; off <<= 1) tb += __shfl_xor(tb, off);
  const float bgp = bg[0] + tb;

  // gate B-frag: col 0 = wg2, other cols 0
  bf16x8 wgf[2];
#pragma unroll
  for (int ks = 0; ks < 2; ++ks) {
    bf16x8 t;
#pragma unroll
    for (int jj = 0; jj < 8; ++jj) {
      float v = __shfl(wgl, 32 * ks + 8 * g + jj);
      t[jj] = (r16 == 0) ? (__bf16)v : (__bf16)0.0f;
    }
    wgf[ks] = t;
  }

  for (int s = wid; s < N; s += nw) {
    const int start = row_start[s];
    const int end = row_start[s + 1];

    // u'[k] for this lane's A-frag slots (k = 32ks + 8g + jj)
    float uf[16];
#pragma unroll
    for (int ks = 0; ks < 2; ++ks) {
      const bf16x8 uv = *(const bf16x8*)(Ub + (size_t)s * 64 + 32 * ks + 8 * g);
#pragma unroll
      for (int jj = 0; jj < 8; ++jj) uf[ks * 8 + jj] = (float)uv[jj];
    }

    float m = -INFINITY, ssum = 0.f;
    float accc[4] = {0.f, 0.f, 0.f, 0.f};

    const int nT = (end - start + 15) >> 4;
    for (int t = 0; t < nT; ++t) {
      const int base = start + t * 16;
      const int er = base + r16;
      const int nb = (er < end) ? nbr_idx[er] : 0;
      const float awr = atom_w[nb];

      // H tile directly in A-frag order: H[e][k] = leaky(u'[k] + Y[nb_e][k])
      bf16x8 ah[2];
#pragma unroll
      for (int ks = 0; ks < 2; ++ks) {
        const bf16x8 yv = *(const bf16x8*)(Yb + (size_t)nb * 64 + 32 * ks + 8 * g);
        bf16x8 a;
#pragma unroll
        for (int jj = 0; jj < 8; ++jj) {
          float hf = uf[ks * 8 + jj] + (float)yv[jj];
          hf = fmaxf(hf, 0.01f * hf);          // leaky_relu (slope 0.01)
          a[jj] = (__bf16)hf;
        }
        ah[ks] = a;
      }

      f32x4 facc[4]; f32x4 gacc = (f32x4)0.0f;
#pragma unroll
      for (int c = 0; c < 4; ++c) facc[c] = (f32x4)0.0f;
#pragma unroll
      for (int ks = 0; ks < 2; ++ks) {
#pragma unroll
        for (int c = 0; c < 4; ++c)
          facc[c] = __builtin_amdgcn_mfma_f32_16x16x32_bf16(ah[ks], w2f[ks][c], facc[c], 0, 0, 0);
        gacc = __builtin_amdgcn_mfma_f32_16x16x32_bf16(ah[ks], wgf[ks], gacc, 0, 0, 0);
      }

      // broadcast gates (live in col 0 -> lanes r16==0) and atom weights
      const int gbase = lane & 0x30;
      float gj[4], aw4[4];
#pragma unroll
      for (int j = 0; j < 4; ++j) gj[j] = __shfl(gacc[j], gbase) + bgp;
#pragma unroll
      for (int j = 0; j < 4; ++j) aw4[j] = __shfl(awr, 4 * g + j);
#pragma unroll
      for (int j = 0; j < 4; ++j) {
        int row = 4 * g + j;
        if (base + row >= end) gj[j] = -INFINITY;
      }

      float mt = fmaxf(fmaxf(gj[0], gj[1]), fmaxf(gj[2], gj[3]));
      mt = fmaxf(mt, __shfl_xor(mt, 16));
      mt = fmaxf(mt, __shfl_xor(mt, 32));

      const float nm = fmaxf(m, mt);
      const float sc = __expf(m - nm);      // m = -inf first tile -> 0
#pragma unroll
      for (int c = 0; c < 4; ++c) accc[c] *= sc;
      ssum *= sc;

      float wj[4], wsum = 0.f;
#pragma unroll
      for (int j = 0; j < 4; ++j) {
        wj[j] = aw4[j] * __expf(gj[j] - nm);  // -inf rows -> 0
        wsum += wj[j];
      }
      ssum += wsum;
#pragma unroll
      for (int c = 0; c < 4; ++c) {
        float a = accc[c];
#pragma unroll
        for (int j = 0; j < 4; ++j) a = fmaf(wj[j], facc[c][j], a);
        accc[c] = fmaf(b2c[c], wsum, a);     // fold +b2 into F
      }
      m = nm;
    }

    // reduce partial sums across the 4 row-groups
#pragma unroll
    for (int c = 0; c < 4; ++c) {
      accc[c] += __shfl_xor(accc[c], 16);
      accc[c] += __shfl_xor(accc[c], 32);
    }
    ssum += __shfl_xor(ssum, 16);
    ssum += __shfl_xor(ssum, 32);

    // lane's output dim = lane = 16*g + r16 -> chunk c = g
    float val = accc[0];
    val = (g == 1) ? accc[1] : val;
    val = (g == 2) ? accc[2] : val;
    val = (g == 3) ? accc[3] : val;

    out[(size_t)s * 64 + lane] = val / (ssum + 1e-13f) + atom_fea[(size_t)s * 64 + lane];
  }
}

extern "C" void kernel_launch(void* const* d_in, const int* in_sizes, int n_in,
                              void* d_out, int out_size, void* d_ws, size_t ws_size,
                              hipStream_t stream) {
  const float* atom_w   = (const float*)d_in[0];
  const float* atom_fea = (const float*)d_in[1];
  const int*   self_idx = (const int*)d_in[2];
  const int*   nbr_idx  = (const int*)d_in[3];
  const float* W1 = (const float*)d_in[4];
  const float* b1 = (const float*)d_in[5];
  const float* W2 = (const float*)d_in[6];
  const float* b2 = (const float*)d_in[7];
  const float* Wg = (const float*)d_in[8];
  const float* bg = (const float*)d_in[9];
  float* out = (float*)d_out;

  const int N = in_sizes[0];   // atom_weights is (N,1)
  const int M = in_sizes[2];   // self_fea_idx is (M,)

  char* ws = (char*)d_ws;
  int* row_start = (int*)ws;
  size_t off = ((size_t)(N + 1) * sizeof(int) + 255) & ~(size_t)255;
  __bf16* Ub = (__bf16*)(ws + off);
  __bf16* Yb = Ub + (size_t)N * 64;

  hipLaunchKernelGGL(build_row_start, dim3((M + 255) / 256), dim3(256), 0,
                     stream, self_idx, row_start, M, N);
  hipLaunchKernelGGL(precompute_uy, dim3(512), dim3(256), 0, stream,
                     atom_fea, W1, b1, Ub, Yb, N);
  hipLaunchKernelGGL(fused_pool, dim3(2048), dim3(256), 0, stream,
                     atom_w, atom_fea, nbr_idx, W2, b2, Wg, bg,
                     row_start, Ub, Yb, out, N);
}

// Round 4
// 150.210 us; speedup vs baseline: 2.8806x; 2.8806x over previous
//
#include <hip/hip_runtime.h>
#include <math.h>

typedef float f32x4 __attribute__((ext_vector_type(4)));
typedef __bf16 bf16x8 __attribute__((ext_vector_type(8)));

// ---------------------------------------------------------------------------
// CSR row offsets from sorted self_fea_idx. row_start[N] = M.
// ---------------------------------------------------------------------------
__global__ void build_row_start(const int* __restrict__ self_idx,
                                int* __restrict__ row_start, int M, int N) {
  int i = blockIdx.x * blockDim.x + threadIdx.x;
  if (i >= M) return;
  int cur = self_idx[i];
  int prev = (i == 0) ? -1 : self_idx[i - 1];
  for (int j = prev + 1; j <= cur; ++j) row_start[j] = i;
  if (i == M - 1) {
    for (int j = cur + 1; j <= N; ++j) row_start[j] = M;
  }
}

// ---------------------------------------------------------------------------
// Phase A: per-atom precompute of layer-1 halves (bf16 in ws).
//   U'[a][d] = sum_k X[a][k]*W1[k][d] + b1[d]
//   Y [a][d] = sum_k X[a][k]*W1[64+k][d]
// MFMA 16x16x32; A-frag: lane holds A[row=lane&15][k=(lane>>4)*8+j].
// ---------------------------------------------------------------------------
__global__ __launch_bounds__(256, 2)
void precompute_uy(const float* __restrict__ atom_fea,
                   const float* __restrict__ W1,
                   const float* __restrict__ b1,
                   __bf16* __restrict__ Ub, __bf16* __restrict__ Yb, int N) {
  const int lane = threadIdx.x & 63;
  const int r16 = lane & 15, g = lane >> 4;
  const int wid = (blockIdx.x * blockDim.x + threadIdx.x) >> 6;
  const int nw = (gridDim.x * blockDim.x) >> 6;

  bf16x8 wt[2][4], wb[2][4];
#pragma unroll
  for (int ks = 0; ks < 2; ++ks)
#pragma unroll
    for (int c = 0; c < 4; ++c) {
      bf16x8 t, b;
#pragma unroll
      for (int jj = 0; jj < 8; ++jj) {
        int k = 32 * ks + 8 * g + jj;
        t[jj] = (__bf16)W1[(size_t)k * 64 + 16 * c + r16];
        b[jj] = (__bf16)W1[(size_t)(64 + k) * 64 + 16 * c + r16];
      }
      wt[ks][c] = t; wb[ks][c] = b;
    }
  float b1c[4];
#pragma unroll
  for (int c = 0; c < 4; ++c) b1c[c] = b1[16 * c + r16];

  const int nTiles = (N + 15) >> 4;
  for (int tile = wid; tile < nTiles; tile += nw) {
    const int a0 = tile * 16;
    int arow = a0 + r16; if (arow >= N) arow = N - 1;

    bf16x8 af[2];
#pragma unroll
    for (int ks = 0; ks < 2; ++ks) {
      const float* p = atom_fea + (size_t)arow * 64 + 32 * ks + 8 * g;
      f32x4 x0 = *(const f32x4*)p;
      f32x4 x1 = *(const f32x4*)(p + 4);
      bf16x8 a;
#pragma unroll
      for (int jj = 0; jj < 4; ++jj) { a[jj] = (__bf16)x0[jj]; a[4 + jj] = (__bf16)x1[jj]; }
      af[ks] = a;
    }

    f32x4 uacc[4], yacc[4];
#pragma unroll
    for (int c = 0; c < 4; ++c) { uacc[c] = (f32x4)0.0f; yacc[c] = (f32x4)0.0f; }
#pragma unroll
    for (int ks = 0; ks < 2; ++ks)
#pragma unroll
      for (int c = 0; c < 4; ++c) {
        uacc[c] = __builtin_amdgcn_mfma_f32_16x16x32_bf16(af[ks], wt[ks][c], uacc[c], 0, 0, 0);
        yacc[c] = __builtin_amdgcn_mfma_f32_16x16x32_bf16(af[ks], wb[ks][c], yacc[c], 0, 0, 0);
      }

#pragma unroll
    for (int c = 0; c < 4; ++c)
#pragma unroll
      for (int j = 0; j < 4; ++j) {
        int row = a0 + 4 * g + j;
        if (row < N) {
          Ub[(size_t)row * 64 + 16 * c + r16] = (__bf16)(uacc[c][j] + b1c[c]);
          Yb[(size_t)row * 64 + 16 * c + r16] = (__bf16)yacc[c][j];
        }
      }
  }
}

// ---------------------------------------------------------------------------
// Main fused kernel. One wave per segment; 16-edge MFMA tiles; online softmax.
// Y-row gather is COALESCED (8 adjacent lanes fetch one full 128B row) and
// staged through a wave-private 2KB LDS buffer with XOR swizzle
// (chunk ^= row&7) so both ds_write_b128 and ds_read_b128 are conflict-free.
// 4 independent waves per block (no barriers, LDS is wave-private).
// ---------------------------------------------------------------------------
__global__ __launch_bounds__(256, 4)
void fused_pool(const float* __restrict__ atom_w,
                const float* __restrict__ atom_fea,
                const int* __restrict__ nbr_idx,
                const float* __restrict__ W2,
                const float* __restrict__ b2,
                const float* __restrict__ Wg,
                const float* __restrict__ bg,
                const int* __restrict__ row_start,
                const __bf16* __restrict__ Ub,
                const __bf16* __restrict__ Yb,
                float* __restrict__ out, int N) {
  const int tid = threadIdx.x;
  const int lane = tid & 63;
  const int r16 = lane & 15, g = lane >> 4;
  const int wslot = tid >> 6;
  const int wid = (blockIdx.x * blockDim.x + tid) >> 6;
  const int nw = (gridDim.x * blockDim.x) >> 6;

  __shared__ __align__(16) unsigned char ybuf_all[4][2048];
  unsigned char* const ybuf = ybuf_all[wslot];

  // W2 B-frags
  bf16x8 w2f[2][4];
#pragma unroll
  for (int ks = 0; ks < 2; ++ks)
#pragma unroll
    for (int c = 0; c < 4; ++c) {
      bf16x8 t;
#pragma unroll
      for (int jj = 0; jj < 8; ++jj) {
        int k = 32 * ks + 8 * g + jj;
        t[jj] = (__bf16)W2[(size_t)k * 64 + 16 * c + r16];
      }
      w2f[ks][c] = t;
    }
  float b2c[4];
#pragma unroll
  for (int c = 0; c < 4; ++c) b2c[c] = b2[16 * c + r16];

  // wg2[k] = sum_d W2[k][d]*Wg[d]  (lane holds k = lane)
  float wgl = 0.f;
  {
    const float* w2row = W2 + (size_t)lane * 64;
#pragma unroll
    for (int d = 0; d < 64; ++d) wgl = fmaf(w2row[d], Wg[d], wgl);
  }
  // bgp = bg + sum_d b2[d]*Wg[d]
  float tb = b2[lane] * Wg[lane];
#pragma unroll
  for (int off = 1; off < 64; off <<= 1) tb += __shfl_xor(tb, off);
  const float bgp = bg[0] + tb;

  // gate B-frag: col 0 = wg2, other cols 0
  bf16x8 wgf[2];
#pragma unroll
  for (int ks = 0; ks < 2; ++ks) {
    bf16x8 t;
#pragma unroll
    for (int jj = 0; jj < 8; ++jj) {
      float v = __shfl(wgl, 32 * ks + 8 * g + jj);
      t[jj] = (r16 == 0) ? (__bf16)v : (__bf16)0.0f;
    }
    wgf[ks] = t;
  }

  const int grow = lane >> 3;   // gather: row within 8-row group
  const int gch = lane & 7;     // gather: 16B chunk within 128B row

  for (int s = wid; s < N; s += nw) {
    const int start = row_start[s];
    const int end = row_start[s + 1];

    // u'[k] for this lane's A-frag slots (k = 32ks + 8g + jj)
    float uf[16];
#pragma unroll
    for (int ks = 0; ks < 2; ++ks) {
      const bf16x8 uv = *(const bf16x8*)(Ub + (size_t)s * 64 + 32 * ks + 8 * g);
#pragma unroll
      for (int jj = 0; jj < 8; ++jj) uf[ks * 8 + jj] = (float)uv[jj];
    }

    float m = -INFINITY, ssum = 0.f;
    float accc[4] = {0.f, 0.f, 0.f, 0.f};

    const int nT = (end - start + 15) >> 4;
    for (int t = 0; t < nT; ++t) {
      const int base = start + t * 16;

      // ---- coalesced Y gather -> swizzled LDS ----
#pragma unroll
      for (int i = 0; i < 2; ++i) {
        const int ri = 8 * i + grow;
        const int e = base + ri;
        const int nb = (e < end) ? nbr_idx[e] : 0;
        const f32x4 v = *(const f32x4*)(Yb + (size_t)nb * 64 + gch * 8);
        *(f32x4*)(ybuf + ri * 128 + ((gch ^ (ri & 7)) << 4)) = v;
      }

      // aw for softmax lanes (edge = r16)
      const int er = base + r16;
      const int nbw = (er < end) ? nbr_idx[er] : 0;
      const float awr = atom_w[nbw];

      // ---- H tile in A-frag order from LDS: H[e][k]=leaky(u'[k]+Y[nb_e][k])
      bf16x8 ah[2];
#pragma unroll
      for (int ks = 0; ks < 2; ++ks) {
        const int cr = ks * 4 + g;
        const bf16x8 yv = *(const bf16x8*)(ybuf + r16 * 128 + ((cr ^ (r16 & 7)) << 4));
        bf16x8 a;
#pragma unroll
        for (int jj = 0; jj < 8; ++jj) {
          float hf = uf[ks * 8 + jj] + (float)yv[jj];
          hf = fmaxf(hf, 0.01f * hf);          // leaky_relu (slope 0.01)
          a[jj] = (__bf16)hf;
        }
        ah[ks] = a;
      }

      f32x4 facc[4]; f32x4 gacc = (f32x4)0.0f;
#pragma unroll
      for (int c = 0; c < 4; ++c) facc[c] = (f32x4)0.0f;
#pragma unroll
      for (int ks = 0; ks < 2; ++ks) {
#pragma unroll
        for (int c = 0; c < 4; ++c)
          facc[c] = __builtin_amdgcn_mfma_f32_16x16x32_bf16(ah[ks], w2f[ks][c], facc[c], 0, 0, 0);
        gacc = __builtin_amdgcn_mfma_f32_16x16x32_bf16(ah[ks], wgf[ks], gacc, 0, 0, 0);
      }

      // broadcast gates (col 0 -> lanes r16==0) and atom weights
      const int gbase = lane & 0x30;
      float gj[4], aw4[4];
#pragma unroll
      for (int j = 0; j < 4; ++j) gj[j] = __shfl(gacc[j], gbase) + bgp;
#pragma unroll
      for (int j = 0; j < 4; ++j) aw4[j] = __shfl(awr, 4 * g + j);
#pragma unroll
      for (int j = 0; j < 4; ++j) {
        if (base + 4 * g + j >= end) gj[j] = -INFINITY;
      }

      float mt = fmaxf(fmaxf(gj[0], gj[1]), fmaxf(gj[2], gj[3]));
      mt = fmaxf(mt, __shfl_xor(mt, 16));
      mt = fmaxf(mt, __shfl_xor(mt, 32));

      const float nm = fmaxf(m, mt);
      const float sc = __expf(m - nm);      // m = -inf first tile -> 0
#pragma unroll
      for (int c = 0; c < 4; ++c) accc[c] *= sc;
      ssum *= sc;

      float wj[4], wsum = 0.f;
#pragma unroll
      for (int j = 0; j < 4; ++j) {
        wj[j] = aw4[j] * __expf(gj[j] - nm);  // -inf rows -> 0
        wsum += wj[j];
      }
      ssum += wsum;
#pragma unroll
      for (int c = 0; c < 4; ++c) {
        float a = accc[c];
#pragma unroll
        for (int j = 0; j < 4; ++j) a = fmaf(wj[j], facc[c][j], a);
        accc[c] = fmaf(b2c[c], wsum, a);     // fold +b2 into F
      }
      m = nm;
    }

    // reduce partial sums across the 4 row-groups
#pragma unroll
    for (int c = 0; c < 4; ++c) {
      accc[c] += __shfl_xor(accc[c], 16);
      accc[c] += __shfl_xor(accc[c], 32);
    }
    ssum += __shfl_xor(ssum, 16);
    ssum += __shfl_xor(ssum, 32);

    // lane's output dim = lane = 16*g + r16 -> chunk c = g
    float val = accc[0];
    val = (g == 1) ? accc[1] : val;
    val = (g == 2) ? accc[2] : val;
    val = (g == 3) ? accc[3] : val;

    out[(size_t)s * 64 + lane] = val / (ssum + 1e-13f) + atom_fea[(size_t)s * 64 + lane];
  }
}

extern "C" void kernel_launch(void* const* d_in, const int* in_sizes, int n_in,
                              void* d_out, int out_size, void* d_ws, size_t ws_size,
                              hipStream_t stream) {
  const float* atom_w   = (const float*)d_in[0];
  const float* atom_fea = (const float*)d_in[1];
  const int*   self_idx = (const int*)d_in[2];
  const int*   nbr_idx  = (const int*)d_in[3];
  const float* W1 = (const float*)d_in[4];
  const float* b1 = (const float*)d_in[5];
  const float* W2 = (const float*)d_in[6];
  const float* b2 = (const float*)d_in[7];
  const float* Wg = (const float*)d_in[8];
  const float* bg = (const float*)d_in[9];
  float* out = (float*)d_out;

  const int N = in_sizes[0];   // atom_weights is (N,1)
  const int M = in_sizes[2];   // self_fea_idx is (M,)

  char* ws = (char*)d_ws;
  int* row_start = (int*)ws;
  size_t off = ((size_t)(N + 1) * sizeof(int) + 255) & ~(size_t)255;
  __bf16* Ub = (__bf16*)(ws + off);
  __bf16* Yb = Ub + (size_t)N * 64;

  hipLaunchKernelGGL(build_row_start, dim3((M + 255) / 256), dim3(256), 0,
                     stream, self_idx, row_start, M, N);
  hipLaunchKernelGGL(precompute_uy, dim3(512), dim3(256), 0, stream,
                     atom_fea, W1, b1, Ub, Yb, N);
  hipLaunchKernelGGL(fused_pool, dim3(2048), dim3(256), 0, stream,
                     atom_w, atom_fea, nbr_idx, W2, b2, Wg, bg,
                     row_start, Ub, Yb, out, N);
}

// Round 5
// 107.480 us; speedup vs baseline: 4.0259x; 1.3976x over previous
//
#include <hip/hip_runtime.h>
#include <math.h>

typedef float f32x4 __attribute__((ext_vector_type(4)));
typedef __bf16 bf16x8 __attribute__((ext_vector_type(8)));

// ---------------------------------------------------------------------------
// CSR row offsets from sorted self_fea_idx. row_start[N] = M.
// ---------------------------------------------------------------------------
__global__ void build_row_start(const int* __restrict__ self_idx,
                                int* __restrict__ row_start, int M, int N) {
  int i = blockIdx.x * blockDim.x + threadIdx.x;
  if (i >= M) return;
  int cur = self_idx[i];
  int prev = (i == 0) ? -1 : self_idx[i - 1];
  for (int j = prev + 1; j <= cur; ++j) row_start[j] = i;
  if (i == M - 1) {
    for (int j = cur + 1; j <= N; ++j) row_start[j] = M;
  }
}

// ---------------------------------------------------------------------------
// Phase A: per-atom precompute of layer-1 halves (bf16 in ws) and a
// B-frag-packed copy of W2 so the main kernel can load its MFMA fragments
// with one dwordx4 per fragment.
//   U'[a][d] = sum_k X[a][k]*W1[k][d] + b1[d]
//   Y [a][d] = sum_k X[a][k]*W1[64+k][d]
//   W2pack[(ks*4+c)*64 + lane][0..7] = W2[32ks+8g+j][16c+r16], lane=16g+r16
// ---------------------------------------------------------------------------
__global__ __launch_bounds__(256, 2)
void precompute_uy(const float* __restrict__ atom_fea,
                   const float* __restrict__ W1,
                   const float* __restrict__ b1,
                   const float* __restrict__ W2,
                   __bf16* __restrict__ Ub, __bf16* __restrict__ Yb,
                   __bf16* __restrict__ W2pack, int N) {
  const int lane = threadIdx.x & 63;
  const int r16 = lane & 15, g = lane >> 4;
  const int wid = (blockIdx.x * blockDim.x + threadIdx.x) >> 6;
  const int nw = (gridDim.x * blockDim.x) >> 6;

  if (wid == 0) {  // pack W2 into B-frag order (8 KB, once)
#pragma unroll
    for (int ks = 0; ks < 2; ++ks)
#pragma unroll
      for (int c = 0; c < 4; ++c) {
        bf16x8 t;
#pragma unroll
        for (int jj = 0; jj < 8; ++jj)
          t[jj] = (__bf16)W2[(size_t)(32 * ks + 8 * g + jj) * 64 + 16 * c + r16];
        *(bf16x8*)(W2pack + ((size_t)(ks * 4 + c) * 64 + lane) * 8) = t;
      }
  }

  bf16x8 wt[2][4], wb[2][4];
#pragma unroll
  for (int ks = 0; ks < 2; ++ks)
#pragma unroll
    for (int c = 0; c < 4; ++c) {
      bf16x8 t, b;
#pragma unroll
      for (int jj = 0; jj < 8; ++jj) {
        int k = 32 * ks + 8 * g + jj;
        t[jj] = (__bf16)W1[(size_t)k * 64 + 16 * c + r16];
        b[jj] = (__bf16)W1[(size_t)(64 + k) * 64 + 16 * c + r16];
      }
      wt[ks][c] = t; wb[ks][c] = b;
    }
  float b1c[4];
#pragma unroll
  for (int c = 0; c < 4; ++c) b1c[c] = b1[16 * c + r16];

  const int nTiles = (N + 15) >> 4;
  for (int tile = wid; tile < nTiles; tile += nw) {
    const int a0 = tile * 16;
    int arow = a0 + r16; if (arow >= N) arow = N - 1;

    bf16x8 af[2];
#pragma unroll
    for (int ks = 0; ks < 2; ++ks) {
      const float* p = atom_fea + (size_t)arow * 64 + 32 * ks + 8 * g;
      f32x4 x0 = *(const f32x4*)p;
      f32x4 x1 = *(const f32x4*)(p + 4);
      bf16x8 a;
#pragma unroll
      for (int jj = 0; jj < 4; ++jj) { a[jj] = (__bf16)x0[jj]; a[4 + jj] = (__bf16)x1[jj]; }
      af[ks] = a;
    }

    f32x4 uacc[4], yacc[4];
#pragma unroll
    for (int c = 0; c < 4; ++c) { uacc[c] = (f32x4)0.0f; yacc[c] = (f32x4)0.0f; }
#pragma unroll
    for (int ks = 0; ks < 2; ++ks)
#pragma unroll
      for (int c = 0; c < 4; ++c) {
        uacc[c] = __builtin_amdgcn_mfma_f32_16x16x32_bf16(af[ks], wt[ks][c], uacc[c], 0, 0, 0);
        yacc[c] = __builtin_amdgcn_mfma_f32_16x16x32_bf16(af[ks], wb[ks][c], yacc[c], 0, 0, 0);
      }

#pragma unroll
    for (int c = 0; c < 4; ++c)
#pragma unroll
      for (int j = 0; j < 4; ++j) {
        int row = a0 + 4 * g + j;
        if (row < N) {
          Ub[(size_t)row * 64 + 16 * c + r16] = (__bf16)(uacc[c][j] + b1c[c]);
          Yb[(size_t)row * 64 + 16 * c + r16] = (__bf16)yacc[c][j];
        }
      }
  }
}

// ---------------------------------------------------------------------------
// Main fused kernel. One wave per segment.
// Algebraic restructure: pooled = (sum_e w_e H_e) @ W2 + (sum_e w_e) b2,
// with w_e = atom_w[nbr_e]*exp(gate_e), gate_e = H_e . wg2 + bgp
// (wg2 = W2@Wg, bgp = bg + b2.Wg). exp WITHOUT max subtraction (softmax is
// shift-invariant; gates are O(+-10), safe in fp32).
// Per 16-edge tile: gather Y rows, build H in f32 regs, per-lane gate dot +
// 2 shfl_xor, one exp, 16 FMA into per-lane z partials. NO MFMA per tile.
// Per segment: pack z -> bf16 A-frag, 8 MFMA against pre-packed W2 frags,
// row-sum via 2 shfl_xor per chunk. Cross-segment prefetch of row_start/Ub.
// ---------------------------------------------------------------------------
__global__ __launch_bounds__(64, 4)
void fused_pool(const float* __restrict__ atom_w,
                const float* __restrict__ atom_fea,
                const int* __restrict__ nbr_idx,
                const float* __restrict__ W2,
                const float* __restrict__ b2,
                const float* __restrict__ Wg,
                const float* __restrict__ bg,
                const int* __restrict__ row_start,
                const __bf16* __restrict__ Ub,
                const __bf16* __restrict__ Yb,
                const __bf16* __restrict__ W2pack,
                float* __restrict__ out, int N) {
  const int lane = threadIdx.x & 63;
  const int r16 = lane & 15, g = lane >> 4;
  const int wid = blockIdx.x;
  const int nw = gridDim.x;

  // wg2[k] = sum_d W2[k][d]*Wg[d]  (lane holds k = lane)
  float wgl = 0.f;
  {
    const float* w2row = W2 + (size_t)lane * 64;
#pragma unroll
    for (int d = 0; d < 64; ++d) wgl = fmaf(w2row[d], Wg[d], wgl);
  }
  // distribute wg2 into this lane's A-frag k-slots: k = 32ks + 8g + jj
  float wgsl[16];
#pragma unroll
  for (int ks = 0; ks < 2; ++ks)
#pragma unroll
    for (int jj = 0; jj < 8; ++jj)
      wgsl[ks * 8 + jj] = __shfl(wgl, 32 * ks + 8 * g + jj);

  // bgp = bg + sum_d b2[d]*Wg[d]
  float tb = b2[lane] * Wg[lane];
#pragma unroll
  for (int off = 1; off < 64; off <<= 1) tb += __shfl_xor(tb, off);
  const float bgp = bg[0] + tb;
  const float b2l = b2[lane];

  // rotating prefetch of next segment's CSR range + U' row
  int s = wid;
  int nStart = 0, nEnd = 0;
  bf16x8 nu0 = {}, nu1 = {};
  if (s < N) {
    nStart = row_start[s];
    nEnd = row_start[s + 1];
    nu0 = *(const bf16x8*)(Ub + (size_t)s * 64 + 8 * g);
    nu1 = *(const bf16x8*)(Ub + (size_t)s * 64 + 32 + 8 * g);
  }

  for (; s < N; s += nw) {
    const int start = nStart, end = nEnd;
    const bf16x8 u0 = nu0, u1 = nu1;
    const float xr = atom_fea[(size_t)s * 64 + lane];  // residual

    const int s2 = s + nw;
    if (s2 < N) {
      nStart = row_start[s2];
      nEnd = row_start[s2 + 1];
      nu0 = *(const bf16x8*)(Ub + (size_t)s2 * 64 + 8 * g);
      nu1 = *(const bf16x8*)(Ub + (size_t)s2 * 64 + 32 + 8 * g);
    }

    float uf[16];
#pragma unroll
    for (int jj = 0; jj < 8; ++jj) {
      uf[jj] = (float)u0[jj];
      uf[8 + jj] = (float)u1[jj];
    }

    float zacc[16];
#pragma unroll
    for (int k = 0; k < 16; ++k) zacc[k] = 0.f;
    float wsum = 0.f;

    for (int base = start; base < end; base += 16) {
      const int er = base + r16;
      const bool valid = er < end;
      const int nb = valid ? nbr_idx[er] : 0;
      const float aw = atom_w[nb];
      const __bf16* yrow = Yb + ((size_t)nb << 6);
      const bf16x8 y0 = *(const bf16x8*)(yrow + 8 * g);
      const bf16x8 y1 = *(const bf16x8*)(yrow + 32 + 8 * g);

      // H in f32 registers (A-frag slot order)
      float hf[16];
#pragma unroll
      for (int jj = 0; jj < 8; ++jj) {
        float a = uf[jj] + (float)y0[jj];
        float b = uf[8 + jj] + (float)y1[jj];
        hf[jj] = fmaxf(a, 0.01f * a);          // leaky_relu slope 0.01
        hf[8 + jj] = fmaxf(b, 0.01f * b);
      }

      // gate_e = H_e . wg2 (+bgp) : per-lane partial + reduce across g-groups
      float p0 = 0.f, p1 = 0.f;
#pragma unroll
      for (int i = 0; i < 8; ++i) {
        p0 = fmaf(hf[i], wgsl[i], p0);
        p1 = fmaf(hf[8 + i], wgsl[8 + i], p1);
      }
      float p = p0 + p1;
      p += __shfl_xor(p, 16);
      p += __shfl_xor(p, 32);

      const float w = valid ? aw * __expf(p + bgp) : 0.f;
      wsum += w;
#pragma unroll
      for (int k = 0; k < 16; ++k) zacc[k] = fmaf(w, hf[k], zacc[k]);
    }

    // ---- segment finalize: pooled = z @ W2 + wsum*b2, then /ssum + x ----
    bf16x8 zf0, zf1;
#pragma unroll
    for (int jj = 0; jj < 8; ++jj) {
      zf0[jj] = (__bf16)zacc[jj];
      zf1[jj] = (__bf16)zacc[8 + jj];
    }

    f32x4 facc[4];
#pragma unroll
    for (int c = 0; c < 4; ++c) facc[c] = (f32x4)0.0f;
#pragma unroll
    for (int c = 0; c < 4; ++c) {
      const bf16x8 wf0 = *(const bf16x8*)(W2pack + ((size_t)(0 * 4 + c) * 64 + lane) * 8);
      const bf16x8 wf1 = *(const bf16x8*)(W2pack + ((size_t)(1 * 4 + c) * 64 + lane) * 8);
      facc[c] = __builtin_amdgcn_mfma_f32_16x16x32_bf16(zf0, wf0, facc[c], 0, 0, 0);
      facc[c] = __builtin_amdgcn_mfma_f32_16x16x32_bf16(zf1, wf1, facc[c], 0, 0, 0);
    }

    // sum over the 16 C rows (Z partial rows): in-lane + cross-g shfl
    float accv[4];
#pragma unroll
    for (int c = 0; c < 4; ++c) {
      float a = (facc[c][0] + facc[c][1]) + (facc[c][2] + facc[c][3]);
      a += __shfl_xor(a, 16);
      a += __shfl_xor(a, 32);
      accv[c] = a;   // = pooled_num[16c + r16] (pre-b2)
    }

    // ssum = sum over r16 groups of per-lane wsum
    float ssum = wsum;
    ssum += __shfl_xor(ssum, 1);
    ssum += __shfl_xor(ssum, 2);
    ssum += __shfl_xor(ssum, 4);
    ssum += __shfl_xor(ssum, 8);

    // lane's output dim d = lane = 16g + r16 -> chunk c = g
    float val = accv[0];
    val = (g == 1) ? accv[1] : val;
    val = (g == 2) ? accv[2] : val;
    val = (g == 3) ? accv[3] : val;
    val = fmaf(ssum, b2l, val);

    out[(size_t)s * 64 + lane] = val / (ssum + 1e-13f) + xr;
  }
}

extern "C" void kernel_launch(void* const* d_in, const int* in_sizes, int n_in,
                              void* d_out, int out_size, void* d_ws, size_t ws_size,
                              hipStream_t stream) {
  const float* atom_w   = (const float*)d_in[0];
  const float* atom_fea = (const float*)d_in[1];
  const int*   self_idx = (const int*)d_in[2];
  const int*   nbr_idx  = (const int*)d_in[3];
  const float* W1 = (const float*)d_in[4];
  const float* b1 = (const float*)d_in[5];
  const float* W2 = (const float*)d_in[6];
  const float* b2 = (const float*)d_in[7];
  const float* Wg = (const float*)d_in[8];
  const float* bg = (const float*)d_in[9];
  float* out = (float*)d_out;

  const int N = in_sizes[0];   // atom_weights is (N,1)
  const int M = in_sizes[2];   // self_fea_idx is (M,)

  char* ws = (char*)d_ws;
  int* row_start = (int*)ws;
  size_t off = ((size_t)(N + 1) * sizeof(int) + 255) & ~(size_t)255;
  __bf16* W2pack = (__bf16*)(ws + off);
  __bf16* Ub = W2pack + 8 * 64 * 8;          // 4 KB after 8KB pack region
  __bf16* Yb = Ub + (size_t)N * 64;

  hipLaunchKernelGGL(build_row_start, dim3((M + 255) / 256), dim3(256), 0,
                     stream, self_idx, row_start, M, N);
  hipLaunchKernelGGL(precompute_uy, dim3(512), dim3(256), 0, stream,
                     atom_fea, W1, b1, W2, Ub, Yb, W2pack, N);
  hipLaunchKernelGGL(fused_pool, dim3(8192), dim3(64), 0, stream,
                     atom_w, atom_fea, nbr_idx, W2, b2, Wg, bg,
                     row_start, Ub, Yb, W2pack, out, N);
}